// Round 1
// baseline (393.871 us; speedup 1.0000x reference)
//
#include <hip/hip_runtime.h>

// MPRelativeSelfMultiheadAttn: hypernet weight-gen + qkv/r projections +
// relative-position flash attention (fused rel_shift + online softmax) + out proj.
// All matmuls in fp16 MFMA (16x16x32), fp32 accumulate. T=1024,B=2,E=1024,H=16,D=64.

typedef _Float16 h16;
typedef _Float16 h16x8 __attribute__((ext_vector_type(8)));
typedef _Float16 h16x4 __attribute__((ext_vector_type(4)));
typedef float f32x4 __attribute__((ext_vector_type(4)));
typedef uint4 v4u;

static __device__ __forceinline__ f32x4 mfma16(h16x8 a, h16x8 b, f32x4 c) {
  return __builtin_amdgcn_mfma_f32_16x16x32_f16(a, b, c, 0, 0, 0);
}

// ---------------- hypernet: derived weights = weight_table @ factor ----------------
__global__ __launch_bounds__(256) void hypernet_kernel(
    const float* __restrict__ fac,
    const float* __restrict__ w_in, const float* __restrict__ w_pos,
    const float* __restrict__ w_out, const float* __restrict__ b_in_w,
    const float* __restrict__ b_pos_w, const float* __restrict__ b_out_w,
    const float* __restrict__ rw_w, const float* __restrict__ rr_w,
    h16* __restrict__ Win, h16* __restrict__ Wpos, h16* __restrict__ Wout,
    float* __restrict__ bin, float* __restrict__ bpos, float* __restrict__ bout,
    float* __restrict__ rw, float* __restrict__ rr)
{
  int idx = blockIdx.x * 256 + threadIdx.x;
  float f0=fac[0],f1=fac[1],f2=fac[2],f3=fac[3],f4=fac[4],f5=fac[5],f6=fac[6],f7=fac[7];
#define DOT8(p) ((p)[0]*f0+(p)[1]*f1+(p)[2]*f2+(p)[3]*f3+(p)[4]*f4+(p)[5]*f5+(p)[6]*f6+(p)[7]*f7)
  if (idx < 3145728) { const float* p = w_in  + (size_t)idx*8; Win[idx]  = (h16)DOT8(p); return; }
  idx -= 3145728;
  if (idx < 1048576) { const float* p = w_pos + (size_t)idx*8; Wpos[idx] = (h16)DOT8(p); return; }
  idx -= 1048576;
  if (idx < 1048576) { const float* p = w_out + (size_t)idx*8; Wout[idx] = (h16)DOT8(p); return; }
  idx -= 1048576;
  if (idx < 3072) { bin[idx]  = DOT8(b_in_w  + (size_t)idx*8); return; }
  idx -= 3072;
  if (idx < 1024) { bpos[idx] = DOT8(b_pos_w + (size_t)idx*8); return; }
  idx -= 1024;
  if (idx < 1024) { bout[idx] = DOT8(b_out_w + (size_t)idx*8); return; }
  idx -= 1024;
  if (idx < 1024) { rw[idx]   = DOT8(rw_w    + (size_t)idx*8); return; }
  idx -= 1024;
  if (idx < 1024) { rr[idx]   = DOT8(rr_w    + (size_t)idx*8); return; }
#undef DOT8
}

// ---------------- fp32 -> fp16 cast ----------------
__global__ __launch_bounds__(256) void cvt_f2h_kernel(
    const float* __restrict__ in, h16* __restrict__ out, int n4)
{
  int i = blockIdx.x * 256 + threadIdx.x;
  if (i >= n4) return;
  float4 v = reinterpret_cast<const float4*>(in)[i];
  h16x4 o = { (h16)v.x, (h16)v.y, (h16)v.z, (h16)v.w };
  reinterpret_cast<h16x4*>(out)[i] = o;
}

// ---------------- C[MxN] = A[MxK] * Bw[NxK]^T + bias[N], fp16 MFMA ----------------
// 128x128 block tile, 4 waves in 2x2, each wave 64x64 (4x4 mfma tiles). K % 64 == 0, N % 128 == 0.
__global__ __launch_bounds__(256) void gemm_bt_kernel(
    const h16* __restrict__ A, const h16* __restrict__ Bw,
    const float* __restrict__ bias, float* __restrict__ C,
    int M, int N, int K)
{
  __shared__ __align__(16) h16 a_sm[128*72];   // pad 64->72: 2-way LDS conflicts only (free)
  __shared__ __align__(16) h16 b_sm[128*72];
  const int tid = threadIdx.x, lane = tid & 63, wave = tid >> 6;
  const int quad = lane >> 4, t16 = lane & 15;
  const int wm = wave >> 1, wn = wave & 1;
  const int m0 = blockIdx.y * 128, n0 = blockIdx.x * 128;
  const int srow = tid >> 2, scol = (tid & 3) * 16;

  f32x4 acc[4][4];
#pragma unroll
  for (int i = 0; i < 4; ++i)
#pragma unroll
    for (int j = 0; j < 4; ++j) acc[i][j] = (f32x4){0.f,0.f,0.f,0.f};

  for (int k0 = 0; k0 < K; k0 += 64) {
    __syncthreads();
#pragma unroll
    for (int p = 0; p < 2; ++p) {
      int r = srow + p*64;
      int gm = m0 + r;
      v4u z0 = {0,0,0,0}, z1 = {0,0,0,0};
      if (gm < M) {
        const v4u* s = reinterpret_cast<const v4u*>(A + (size_t)gm*K + k0 + scol);
        z0 = s[0]; z1 = s[1];
      }
      v4u* da = reinterpret_cast<v4u*>(a_sm + r*72 + scol);
      da[0] = z0; da[1] = z1;
      const v4u* sb = reinterpret_cast<const v4u*>(Bw + (size_t)(n0 + r)*K + k0 + scol);
      v4u w0 = sb[0], w1 = sb[1];
      v4u* db = reinterpret_cast<v4u*>(b_sm + r*72 + scol);
      db[0] = w0; db[1] = w1;
    }
    __syncthreads();
#pragma unroll
    for (int kc = 0; kc < 2; ++kc) {
      h16x8 af[4], bfr[4];
#pragma unroll
      for (int i = 0; i < 4; ++i) {
        af[i]  = *reinterpret_cast<const h16x8*>(a_sm + (wm*64 + i*16 + t16)*72 + kc*32 + quad*8);
        bfr[i] = *reinterpret_cast<const h16x8*>(b_sm + (wn*64 + i*16 + t16)*72 + kc*32 + quad*8);
      }
#pragma unroll
      for (int i = 0; i < 4; ++i)
#pragma unroll
        for (int j = 0; j < 4; ++j)
          acc[i][j] = mfma16(af[i], bfr[j], acc[i][j]);
    }
  }
  // epilogue: C/D layout row=(lane>>4)*4+reg, col=lane&15 (m89/m91-verified)
#pragma unroll
  for (int i = 0; i < 4; ++i) {
    int mb = m0 + wm*64 + i*16 + quad*4;
#pragma unroll
    for (int j = 0; j < 4; ++j) {
      int n = n0 + wn*64 + j*16 + t16;
      float bv = bias[n];
#pragma unroll
      for (int r = 0; r < 4; ++r) {
        int m = mb + r;
        if (m < M) C[(size_t)m*N + n] = acc[i][j][r] + bv;
      }
    }
  }
}

// ---------------- split qkv + add rw/rr + per-head layouts, fp16 ----------------
// qrw/qrr/k/v: [BH][T][D]; r: [BH][2048][D] (row 2047 zero-padded)
__global__ __launch_bounds__(256) void split_cvt_kernel(
    const float* __restrict__ qkv, const float* __restrict__ rproj,
    const float* __restrict__ rw, const float* __restrict__ rr,
    h16* __restrict__ qrw, h16* __restrict__ qrr,
    h16* __restrict__ kb, h16* __restrict__ vb, h16* __restrict__ rb)
{
  int idx = blockIdx.x * 256 + threadIdx.x;
  const int NQ = 32*1024*64;  // 2^21
  if (idx < 4*NQ) {
    int sec = idx >> 21;
    int id  = idx & (NQ - 1);
    int d = id & 63, t = (id >> 6) & 1023, bh = id >> 16;
    int b = bh >> 4, h = bh & 15;
    size_t qoff = (size_t)(t*2 + b) * 3072 + h*64 + d;
    if      (sec == 0) qrw[id] = (h16)(qkv[qoff] + rw[h*64+d]);
    else if (sec == 1) qrr[id] = (h16)(qkv[qoff] + rr[h*64+d]);
    else if (sec == 2) kb[id]  = (h16)qkv[qoff + 1024];
    else               vb[id]  = (h16)qkv[qoff + 2048];
    return;
  }
  idx -= 4*NQ;
  if (idx < 32*2048*64) {
    int d = idx & 63, rel = (idx >> 6) & 2047, bh = idx >> 17;
    int b = bh >> 4, h = bh & 15;
    h16 v = (h16)0.f;
    if (rel < 2047) v = (h16)rproj[(size_t)(rel*2 + b) * 1024 + h*64 + d];
    rb[idx] = v;
  }
}

// ---------------- flash attention with relative shift ----------------
// Block: one (bh, 64-row q tile), 4 waves of 16 q-rows each.
// logit(i,j) = [ (q+rw)_i . k_j  +  (q+rr)_i . r_{j-i+1023} ] * 0.125
__global__ __launch_bounds__(256) void flash_kernel(
    const h16* __restrict__ qrw, const h16* __restrict__ qrr,
    const h16* __restrict__ kb, const h16* __restrict__ vb,
    const h16* __restrict__ rb, h16* __restrict__ attn_out)
{
  __shared__ __align__(16) h16 k_sm[64*72];
  __shared__ __align__(16) h16 r_sm[128*72];
  __shared__ __align__(16) h16 vt_sm[64*72];     // v transposed: vt[d][j]
  __shared__ __align__(16) float bd_sm[4*16*84]; // per-wave BD spill; reused for P(fp16)

  const int tid = threadIdx.x, lane = tid & 63, wave = tid >> 6;
  const int quad = lane >> 4, t16 = lane & 15;
  const int bh = blockIdx.y;
  const int i0 = blockIdx.x * 64;
  const size_t base  = (size_t)bh * 1024 * 64;
  const size_t rbase = (size_t)bh * 2048 * 64;
  const int iw = i0 + wave * 16;

  // persistent A-fragments for this wave's 16 q rows (A layout: m=lane&15, k=quad*8+j)
  h16x8 a_rw[2], a_rr[2];
  {
    const h16* p = qrw + base + (size_t)(iw + t16) * 64 + quad * 8;
    a_rw[0] = *reinterpret_cast<const h16x8*>(p);
    a_rw[1] = *reinterpret_cast<const h16x8*>(p + 32);
    const h16* p2 = qrr + base + (size_t)(iw + t16) * 64 + quad * 8;
    a_rr[0] = *reinterpret_cast<const h16x8*>(p2);
    a_rr[1] = *reinterpret_cast<const h16x8*>(p2 + 32);
  }

  f32x4 o_acc[4];
#pragma unroll
  for (int dc = 0; dc < 4; ++dc) o_acc[dc] = (f32x4){0.f,0.f,0.f,0.f};
  float m_run[4] = {-1e30f,-1e30f,-1e30f,-1e30f};
  float l_run[4] = {0.f,0.f,0.f,0.f};

  float* bdw = bd_sm + wave * (16*84);          // wave-private
  h16*   pw  = reinterpret_cast<h16*>(bdw);     // reuse after BD consumed (same-wave ordering)

  const int srow = tid >> 2, scol = (tid & 3) * 16;
  const int cb0 = 3 - wave;  // wave w needs rel-chunks [3-w, 7-w] of the 128-row r tile

  for (int j0 = 0; j0 < 1024; j0 += 64) {
    __syncthreads();
    { // stage K tile
      const v4u* s = reinterpret_cast<const v4u*>(kb + base + (size_t)(j0 + srow)*64 + scol);
      v4u* dst = reinterpret_cast<v4u*>(k_sm + srow*72 + scol);
      dst[0] = s[0]; dst[1] = s[1];
    }
    { // stage V transposed
      union { v4u u4[2]; h16 h[16]; } tv;
      const v4u* s = reinterpret_cast<const v4u*>(vb + base + (size_t)(j0 + srow)*64 + scol);
      tv.u4[0] = s[0]; tv.u4[1] = s[1];
#pragma unroll
      for (int e = 0; e < 16; ++e) vt_sm[(scol + e)*72 + srow] = tv.h[e];
    }
    { // stage R tile: 128 rows from rel0 = j0 - i0 + 960 (always in [0,1920])
      const int rel0 = j0 - i0 + 960;
#pragma unroll
      for (int p = 0; p < 2; ++p) {
        int rrow = srow + p*64;
        const v4u* s = reinterpret_cast<const v4u*>(rb + rbase + (size_t)(rel0 + rrow)*64 + scol);
        v4u* dst = reinterpret_cast<v4u*>(r_sm + rrow*72 + scol);
        dst[0] = s[0]; dst[1] = s[1];
      }
    }
    __syncthreads();

    // AC = (q+rw) . k^T : 16x64 per wave
    f32x4 s_ac[4];
#pragma unroll
    for (int c = 0; c < 4; ++c) {
      s_ac[c] = (f32x4){0.f,0.f,0.f,0.f};
#pragma unroll
      for (int kc = 0; kc < 2; ++kc) {
        h16x8 b = *reinterpret_cast<const h16x8*>(k_sm + (c*16 + t16)*72 + kc*32 + quad*8);
        s_ac[c] = mfma16(a_rw[kc], b, s_ac[c]);
      }
    }
    // BD = (q+rr) . r^T over this wave's 5 rel-chunks (80 rel values)
    f32x4 s_bd[5];
#pragma unroll
    for (int u = 0; u < 5; ++u) {
      s_bd[u] = (f32x4){0.f,0.f,0.f,0.f};
#pragma unroll
      for (int kc = 0; kc < 2; ++kc) {
        h16x8 b = *reinterpret_cast<const h16x8*>(r_sm + ((cb0+u)*16 + t16)*72 + kc*32 + quad*8);
        s_bd[u] = mfma16(a_rr[kc], b, s_bd[u]);
      }
    }
    // spill BD (C-layout) to wave-private LDS: row=quad*4+r, local col = u*16+t16
#pragma unroll
    for (int u = 0; u < 5; ++u)
#pragma unroll
      for (int r = 0; r < 4; ++r)
        bdw[(quad*4 + r)*84 + u*16 + t16] = s_bd[u][r];

    // combine with relative shift: local col = c*16 + t16 + 15 - il  (in [0,78])
    float sv[4][4];
#pragma unroll
    for (int c = 0; c < 4; ++c)
#pragma unroll
      for (int r = 0; r < 4; ++r) {
        int il = quad*4 + r;
        float bdv = bdw[il*84 + c*16 + t16 + 15 - il];
        sv[c][r] = (s_ac[c][r] + bdv) * 0.125f;
      }

    // online softmax (rows live in quad's 16 lanes)
    float alpha[4];
#pragma unroll
    for (int r = 0; r < 4; ++r) {
      float v = fmaxf(fmaxf(sv[0][r], sv[1][r]), fmaxf(sv[2][r], sv[3][r]));
#pragma unroll
      for (int off = 1; off < 16; off <<= 1) v = fmaxf(v, __shfl_xor(v, off, 64));
      float mn = fmaxf(m_run[r], v);
      alpha[r] = __expf(m_run[r] - mn);
      m_run[r] = mn;
    }
#pragma unroll
    for (int r = 0; r < 4; ++r) {
      float s0 = 0.f;
#pragma unroll
      for (int c = 0; c < 4; ++c) {
        float p = __expf(sv[c][r] - m_run[r]);
        sv[c][r] = p; s0 += p;
      }
#pragma unroll
      for (int off = 1; off < 16; off <<= 1) s0 += __shfl_xor(s0, off, 64);
      l_run[r] = l_run[r]*alpha[r] + s0;
    }
#pragma unroll
    for (int dc = 0; dc < 4; ++dc) {
      f32x4 t = o_acc[dc];
#pragma unroll
      for (int r = 0; r < 4; ++r) t[r] *= alpha[r];
      o_acc[dc] = t;
    }
    // P -> LDS (C-layout write), read back as A-fragments (m120 round-trip)
#pragma unroll
    for (int c = 0; c < 4; ++c)
#pragma unroll
      for (int r = 0; r < 4; ++r)
        pw[(quad*4 + r)*72 + c*16 + t16] = (h16)sv[c][r];

    h16x8 ap0 = *reinterpret_cast<const h16x8*>(pw + t16*72 + quad*8);
    h16x8 ap1 = *reinterpret_cast<const h16x8*>(pw + t16*72 + 32 + quad*8);
#pragma unroll
    for (int dc = 0; dc < 4; ++dc) {
      h16x8 bv0 = *reinterpret_cast<const h16x8*>(vt_sm + (dc*16 + t16)*72 + quad*8);
      h16x8 bv1 = *reinterpret_cast<const h16x8*>(vt_sm + (dc*16 + t16)*72 + 32 + quad*8);
      o_acc[dc] = mfma16(ap0, bv0, o_acc[dc]);
      o_acc[dc] = mfma16(ap1, bv1, o_acc[dc]);
    }
  }

  // epilogue: attn_out[(t*B+b)*E + h*64 + d], fp16 for the out-proj GEMM
  const int b = bh >> 4, h = bh & 15;
#pragma unroll
  for (int r = 0; r < 4; ++r) {
    int i = iw + quad*4 + r;
    float inv = 1.f / l_run[r];
#pragma unroll
    for (int dc = 0; dc < 4; ++dc)
      attn_out[(size_t)(i*2 + b)*1024 + h*64 + dc*16 + t16] = (h16)(o_acc[dc][r] * inv);
  }
}

extern "C" void kernel_launch(void* const* d_in, const int* in_sizes, int n_in,
                              void* d_out, int out_size, void* d_ws, size_t ws_size,
                              hipStream_t stream)
{
  const float* input  = (const float*)d_in[0];
  const float* pos    = (const float*)d_in[1];
  const float* fac    = (const float*)d_in[2];
  const float* w_in   = (const float*)d_in[3];
  const float* w_pos  = (const float*)d_in[4];
  const float* w_out  = (const float*)d_in[5];
  const float* bin_w  = (const float*)d_in[6];
  const float* bpos_w = (const float*)d_in[7];
  const float* bout_w = (const float*)d_in[8];
  const float* rw_w   = (const float*)d_in[9];
  const float* rr_w   = (const float*)d_in[10];
  float* out = (float*)d_out;
  (void)in_sizes; (void)n_in; (void)out_size; (void)ws_size;

  // workspace layout (94.4 MB total, all 16B-aligned)
  char* w = (char*)d_ws;
  auto take = [&](size_t bytes) { char* p = w; w += bytes; return p; };
  h16*   Win    = (h16*)take(3145728ull*2);
  h16*   Wpos   = (h16*)take(1048576ull*2);
  h16*   Wout   = (h16*)take(1048576ull*2);
  float* bin    = (float*)take(3072*4);
  float* bpos   = (float*)take(1024*4);
  float* bout   = (float*)take(1024*4);
  float* rw     = (float*)take(1024*4);
  float* rr     = (float*)take(1024*4);
  h16*   in_h   = (h16*)take(2097152ull*2);
  h16*   pos_h  = (h16*)take(4192256ull*2);
  float* qkv    = (float*)take(6291456ull*4);
  float* rproj  = (float*)take(4192256ull*4);
  h16*   qrwb   = (h16*)take(2097152ull*2);
  h16*   qrrb   = (h16*)take(2097152ull*2);
  h16*   kb     = (h16*)take(2097152ull*2);
  h16*   vb     = (h16*)take(2097152ull*2);
  h16*   rb     = (h16*)take(4194304ull*2);
  h16*   attn_h = (h16*)take(2097152ull*2);

  hypernet_kernel<<<20508, 256, 0, stream>>>(fac, w_in, w_pos, w_out, bin_w, bpos_w, bout_w,
                                             rw_w, rr_w, Win, Wpos, Wout, bin, bpos, bout, rw, rr);
  cvt_f2h_kernel<<<2048, 256, 0, stream>>>(input, in_h, 524288);
  cvt_f2h_kernel<<<4094, 256, 0, stream>>>(pos, pos_h, 1048064);
  // qkv = input @ W_in^T + b_in : [2048 x 3072]
  gemm_bt_kernel<<<dim3(24, 16), 256, 0, stream>>>(in_h, Win, bin, qkv, 2048, 3072, 1024);
  // r = pos @ W_pos^T + b_pos : [4094 x 1024]
  gemm_bt_kernel<<<dim3(8, 32), 256, 0, stream>>>(pos_h, Wpos, bpos, rproj, 4094, 1024, 1024);
  split_cvt_kernel<<<49152, 256, 0, stream>>>(qkv, rproj, rw, rr, qrwb, qrrb, kb, vb, rb);
  flash_kernel<<<dim3(16, 32), 256, 0, stream>>>(qrwb, qrrb, kb, vb, rb, attn_h);
  // out = attn_out @ W_out^T + b_out : [2048 x 1024] -> d_out
  gemm_bt_kernel<<<dim3(8, 16), 256, 0, stream>>>(attn_h, Wout, bout, out, 2048, 1024, 1024);
}

// Round 2
// 379.015 us; speedup vs baseline: 1.0392x; 1.0392x over previous
//
#include <hip/hip_runtime.h>

// MPRelativeSelfMultiheadAttn on gfx950.
// hypernet (fp32, BW-bound) -> fp16 MFMA GEMMs with fused per-head epilogues
// -> global V-transpose -> j-split flash attention (rel_shift fused, online
// softmax, global_load_lds staging, 32KB LDS) -> combine -> out GEMM.
// T=1024,B=2,E=1024,H=16,D=64,R=2047.

typedef _Float16 h16;
typedef _Float16 h16x8 __attribute__((ext_vector_type(8)));
typedef _Float16 h16x4 __attribute__((ext_vector_type(4)));
typedef float f32x4 __attribute__((ext_vector_type(4)));

static __device__ __forceinline__ f32x4 mfma16(h16x8 a, h16x8 b, f32x4 c) {
  return __builtin_amdgcn_mfma_f32_16x16x32_f16(a, b, c, 0, 0, 0);
}

// async global->LDS, 16B per lane. LDS dest = wave-uniform base + lane*16.
static __device__ __forceinline__ void gload16(const void* g, void* l) {
  __builtin_amdgcn_global_load_lds((const __attribute__((address_space(1))) void*)g,
                                   (__attribute__((address_space(3))) void*)l, 16, 0, 0);
}

// ---------------- hypernet: derived params = table @ factor ----------------
__global__ __launch_bounds__(256) void hypernet_kernel(
    const float* __restrict__ fac,
    const float* __restrict__ w_in, const float* __restrict__ w_pos,
    const float* __restrict__ w_out, const float* __restrict__ b_in_w,
    const float* __restrict__ b_pos_w, const float* __restrict__ b_out_w,
    const float* __restrict__ rw_w, const float* __restrict__ rr_w,
    h16* __restrict__ Win, h16* __restrict__ Wpos, h16* __restrict__ Wout,
    float* __restrict__ bin, float* __restrict__ bpos, float* __restrict__ bout,
    float* __restrict__ rw, float* __restrict__ rr, h16* __restrict__ rb)
{
  int idx = blockIdx.x * 256 + threadIdx.x;
  float f0=fac[0],f1=fac[1],f2=fac[2],f3=fac[3],f4=fac[4],f5=fac[5],f6=fac[6],f7=fac[7];
#define DOT8(p) ((p)[0]*f0+(p)[1]*f1+(p)[2]*f2+(p)[3]*f3+(p)[4]*f4+(p)[5]*f5+(p)[6]*f6+(p)[7]*f7)
  if (idx < 3145728) { const float* p = w_in  + (size_t)idx*8; Win[idx]  = (h16)DOT8(p); return; }
  idx -= 3145728;
  if (idx < 1048576) { const float* p = w_pos + (size_t)idx*8; Wpos[idx] = (h16)DOT8(p); return; }
  idx -= 1048576;
  if (idx < 1048576) { const float* p = w_out + (size_t)idx*8; Wout[idx] = (h16)DOT8(p); return; }
  idx -= 1048576;
  if (idx < 3072) { bin[idx]  = DOT8(b_in_w  + (size_t)idx*8); return; }
  idx -= 3072;
  if (idx < 1024) { bpos[idx] = DOT8(b_pos_w + (size_t)idx*8); return; }
  idx -= 1024;
  if (idx < 1024) { bout[idx] = DOT8(b_out_w + (size_t)idx*8); return; }
  idx -= 1024;
  if (idx < 1024) { rw[idx]   = DOT8(rw_w    + (size_t)idx*8); return; }
  idx -= 1024;
  if (idx < 1024) { rr[idx]   = DOT8(rr_w    + (size_t)idx*8); return; }
  idx -= 1024;
  if (idx < 2048) { // zero pad row rel=2047 of rb [BH][2048][64]
    rb[(((size_t)(idx >> 6)) << 17) + 2047*64 + (idx & 63)] = (h16)0.f;
  }
#undef DOT8
}

// ---------------- fp32 -> fp16 cast ----------------
__global__ __launch_bounds__(256) void cvt_f2h_kernel(
    const float* __restrict__ in, h16* __restrict__ out, int n4)
{
  int i = blockIdx.x * 256 + threadIdx.x;
  if (i >= n4) return;
  float4 v = reinterpret_cast<const float4*>(in)[i];
  h16x4 o = { (h16)v.x, (h16)v.y, (h16)v.z, (h16)v.w };
  reinterpret_cast<h16x4*>(out)[i] = o;
}

// ---------------- GEMM C = A[MxK] * Bw[NxK]^T, m97-style global_load_lds ----------------
// MODE 0: qkv projection -> writes qrw,qrr,kb,vb (h16, per-head [BH][T][64])
// MODE 1: r projection   -> writes rb (h16, [BH][2048][64], rel=m>>1)
// MODE 2: out projection -> writes Cout fp32 [M][N] + bias
template <int MODE>
__global__ __launch_bounds__(256) void gemm_lds_kernel(
    const h16* __restrict__ A, const h16* __restrict__ Bw,
    const float* __restrict__ bias, int M, int N, int K,
    float* __restrict__ Cout,
    const float* __restrict__ rwv, const float* __restrict__ rrv,
    h16* __restrict__ o0, h16* __restrict__ o1,
    h16* __restrict__ o2, h16* __restrict__ o3)
{
  __shared__ __align__(16) h16 a_sm[128*64];
  __shared__ __align__(16) h16 b_sm[128*64];
  const int tid = threadIdx.x, lane = tid & 63, wave = tid >> 6;
  const int quad = lane >> 4, t16 = lane & 15;
  const int wm = wave >> 1, wn = wave & 1;
  const int m0 = blockIdx.y * 128, n0 = blockIdx.x * 128;
  const int lrow = lane >> 3, lcol = (lane & 7) * 8;

  f32x4 acc[4][4];
#pragma unroll
  for (int i = 0; i < 4; ++i)
#pragma unroll
    for (int j = 0; j < 4; ++j) acc[i][j] = (f32x4){0.f,0.f,0.f,0.f};

  for (int k0 = 0; k0 < K; k0 += 64) {
    __syncthreads();
#pragma unroll
    for (int s = 0; s < 4; ++s) {
      int rbase = wave*32 + s*8;
      gload16(A  + (size_t)(m0 + rbase + lrow)*K + k0 + lcol, a_sm + rbase*64);
      gload16(Bw + (size_t)(n0 + rbase + lrow)*K + k0 + lcol, b_sm + rbase*64);
    }
    __syncthreads();
#pragma unroll
    for (int kc = 0; kc < 2; ++kc) {
      h16x8 af[4], bfr[4];
#pragma unroll
      for (int i = 0; i < 4; ++i) {
        af[i]  = *reinterpret_cast<const h16x8*>(a_sm + (wm*64 + i*16 + t16)*64 + kc*32 + quad*8);
        bfr[i] = *reinterpret_cast<const h16x8*>(b_sm + (wn*64 + i*16 + t16)*64 + kc*32 + quad*8);
      }
#pragma unroll
      for (int i = 0; i < 4; ++i)
#pragma unroll
        for (int j = 0; j < 4; ++j)
          acc[i][j] = mfma16(af[i], bfr[j], acc[i][j]);
    }
  }

  // epilogue: C/D layout row=(lane>>4)*4+reg, col=lane&15
#pragma unroll
  for (int i = 0; i < 4; ++i) {
    int mb = m0 + wm*64 + i*16 + quad*4;
#pragma unroll
    for (int j = 0; j < 4; ++j) {
      int n = n0 + wn*64 + j*16 + t16;
      float bv = bias[n];
      if (MODE == 2) {
#pragma unroll
        for (int r = 0; r < 4; ++r)
          Cout[(size_t)(mb + r)*N + n] = acc[i][j][r] + bv;
      } else if (MODE == 0) {
        int nn = n & 1023, sec = n >> 10, hh = nn >> 6, d = nn & 63;
        float rwb = rwv[nn], rrb = rrv[nn];
#pragma unroll
        for (int r = 0; r < 4; ++r) {
          int m = mb + r, t = m >> 1, b = m & 1;
          size_t off = ((size_t)((b << 4) + hh) << 16) + (t << 6) + d;
          float v = acc[i][j][r] + bv;
          if (sec == 0)      { o0[off] = (h16)(v + rwb); o1[off] = (h16)(v + rrb); }
          else if (sec == 1) { o2[off] = (h16)v; }
          else               { o3[off] = (h16)v; }
        }
      } else { // MODE 1
        int hh = n >> 6, d = n & 63;
#pragma unroll
        for (int r = 0; r < 4; ++r) {
          int m = mb + r;
          if (m < M) {
            int rel = m >> 1, b = m & 1;
            o0[(((size_t)((b << 4) + hh)) << 17) + (rel << 6) + d] = (h16)(acc[i][j][r] + bv);
          }
        }
      }
    }
  }
}

// ---------------- V transpose: vb [BH][T][64] -> vbt [BH][64][T] ----------------
__global__ __launch_bounds__(256) void transpose_v_kernel(
    const h16* __restrict__ vb, h16* __restrict__ vbt)
{
  __shared__ h16 tile[64*72];
  const int bh = blockIdx.y, t0 = blockIdx.x * 64;
  const int r = threadIdx.x >> 3, c = (threadIdx.x & 7) * 8;
  const h16* src = vb + ((size_t)bh << 16) + (size_t)(t0 + r)*64 + c;
  *reinterpret_cast<h16x8*>(tile + r*72 + c)        = *reinterpret_cast<const h16x8*>(src);
  *reinterpret_cast<h16x8*>(tile + (r + 32)*72 + c) = *reinterpret_cast<const h16x8*>(src + 32*64);
  __syncthreads();
  h16x8 o0, o1;
#pragma unroll
  for (int e = 0; e < 8; ++e) {
    o0[e] = tile[(c + e)*72 + r];
    o1[e] = tile[(c + e)*72 + r + 32];
  }
  h16* dst = vbt + ((size_t)bh << 16) + (size_t)r*1024 + t0 + c;
  *reinterpret_cast<h16x8*>(dst)            = o0;
  *reinterpret_cast<h16x8*>(dst + 32*1024)  = o1;
}

// ---------------- flash attention, j-split, rel-shift fused ----------------
// grid (16 q-tiles, 32 bh, 2 j-halves); 4 waves x 16 q-rows.
// logit(i,j) = [ (q+rw)_i.k_j + (q+rr)_i.rb[j-i+1023] ] * 0.125
__global__ __launch_bounds__(256) void flash_kernel(
    const h16* __restrict__ qrw, const h16* __restrict__ qrr,
    const h16* __restrict__ kb, const h16* __restrict__ vbt,
    const h16* __restrict__ rb,
    float* __restrict__ o_part, float* __restrict__ ml_part)
{
  __shared__ __align__(16) h16 k_sm[64*64];
  __shared__ __align__(16) h16 vt_sm[64*64];
  __shared__ __align__(16) h16 r_sm[128*64];   // reused as BD/P spill after barrier

  const int tid = threadIdx.x, lane = tid & 63, wave = tid >> 6;
  const int quad = lane >> 4, t16 = lane & 15;
  const int bh = blockIdx.y, i0 = blockIdx.x * 64, jh = blockIdx.z;
  const size_t base  = (size_t)bh << 16;
  const size_t rbase = (size_t)bh << 17;
  const int iw = i0 + wave * 16;
  const int lrow = lane >> 3, lcol = (lane & 7) * 8;

  h16x8 a_rw[2], a_rr[2];
  {
    const h16* p = qrw + base + (size_t)(iw + t16)*64 + quad*8;
    a_rw[0] = *reinterpret_cast<const h16x8*>(p);
    a_rw[1] = *reinterpret_cast<const h16x8*>(p + 32);
    const h16* p2 = qrr + base + (size_t)(iw + t16)*64 + quad*8;
    a_rr[0] = *reinterpret_cast<const h16x8*>(p2);
    a_rr[1] = *reinterpret_cast<const h16x8*>(p2 + 32);
  }

  f32x4 o_acc[4];
#pragma unroll
  for (int dc = 0; dc < 4; ++dc) o_acc[dc] = (f32x4){0.f,0.f,0.f,0.f};
  float m_run[4] = {-1e30f,-1e30f,-1e30f,-1e30f};
  float l_run[4] = {0.f,0.f,0.f,0.f};

  h16* bdw = r_sm + wave * (16*84);   // wave-private spill (5376 h16 <= 8192)
  const int cb0 = 3 - wave;           // rel-chunks [3-w, 7-w] of the 128-row r tile

  for (int j0 = jh*512; j0 < jh*512 + 512; j0 += 64) {
    __syncthreads();  // prev iter's k/vt/r+spill reads all done
    { // stage K, V^T: rows [wave*16, wave*16+16)
#pragma unroll
      for (int s = 0; s < 2; ++s) {
        int row = wave*16 + s*8;
        gload16(kb  + base + (size_t)(j0 + row + lrow)*64 + lcol, k_sm  + row*64);
        gload16(vbt + base + (size_t)(row + lrow)*1024 + j0 + lcol, vt_sm + row*64);
      }
      const int rel0 = j0 - i0 + 960;  // in [0,1920]
#pragma unroll
      for (int s = 0; s < 4; ++s) {
        int row = wave*32 + s*8;
        gload16(rb + rbase + (size_t)(rel0 + row + lrow)*64 + lcol, r_sm + row*64);
      }
    }
    __syncthreads();

    // AC = (q+rw).k^T : 16x64
    f32x4 s_ac[4];
#pragma unroll
    for (int c = 0; c < 4; ++c) {
      s_ac[c] = (f32x4){0.f,0.f,0.f,0.f};
#pragma unroll
      for (int kc = 0; kc < 2; ++kc) {
        h16x8 b = *reinterpret_cast<const h16x8*>(k_sm + (c*16 + t16)*64 + kc*32 + quad*8);
        s_ac[c] = mfma16(a_rw[kc], b, s_ac[c]);
      }
    }
    // BD over this wave's 5 rel-chunks (80 rel values)
    f32x4 s_bd[5];
#pragma unroll
    for (int u = 0; u < 5; ++u) {
      s_bd[u] = (f32x4){0.f,0.f,0.f,0.f};
#pragma unroll
      for (int kc = 0; kc < 2; ++kc) {
        h16x8 b = *reinterpret_cast<const h16x8*>(r_sm + ((cb0+u)*16 + t16)*64 + kc*32 + quad*8);
        s_bd[u] = mfma16(a_rr[kc], b, s_bd[u]);
      }
    }
    __syncthreads();  // all waves done reading r_sm before spilling into it

    // spill BD (C-layout) h16, stride 84: conflict-free (quad stride 168w = 8 mod 32)
#pragma unroll
    for (int u = 0; u < 5; ++u)
#pragma unroll
      for (int r = 0; r < 4; ++r)
        bdw[(quad*4 + r)*84 + u*16 + t16] = (h16)s_bd[u][r];

    // combine with relative shift: local col = c*16 + t16 + 15 - il
    float sv[4][4];
#pragma unroll
    for (int c = 0; c < 4; ++c)
#pragma unroll
      for (int r = 0; r < 4; ++r) {
        int il = quad*4 + r;
        float bdv = (float)bdw[il*84 + c*16 + t16 + 15 - il];
        sv[c][r] = (s_ac[c][r] + bdv) * 0.125f;
      }

    // online softmax (rows across the quad's 16 lanes)
    float alpha[4];
#pragma unroll
    for (int r = 0; r < 4; ++r) {
      float v = fmaxf(fmaxf(sv[0][r], sv[1][r]), fmaxf(sv[2][r], sv[3][r]));
#pragma unroll
      for (int off = 1; off < 16; off <<= 1) v = fmaxf(v, __shfl_xor(v, off, 64));
      float mn = fmaxf(m_run[r], v);
      alpha[r] = __expf(m_run[r] - mn);
      m_run[r] = mn;
    }
#pragma unroll
    for (int r = 0; r < 4; ++r) {
      float s0 = 0.f;
#pragma unroll
      for (int c = 0; c < 4; ++c) {
        float p = __expf(sv[c][r] - m_run[r]);
        sv[c][r] = p; s0 += p;
      }
#pragma unroll
      for (int off = 1; off < 16; off <<= 1) s0 += __shfl_xor(s0, off, 64);
      l_run[r] = l_run[r]*alpha[r] + s0;
    }
#pragma unroll
    for (int dc = 0; dc < 4; ++dc) {
      f32x4 t = o_acc[dc];
#pragma unroll
      for (int r = 0; r < 4; ++r) t[r] *= alpha[r];
      o_acc[dc] = t;
    }
    // P -> wave-private LDS (stride 72), read back as A-fragments
    h16* pw = bdw;
#pragma unroll
    for (int c = 0; c < 4; ++c)
#pragma unroll
      for (int r = 0; r < 4; ++r)
        pw[(quad*4 + r)*72 + c*16 + t16] = (h16)sv[c][r];

    h16x8 ap0 = *reinterpret_cast<const h16x8*>(pw + t16*72 + quad*8);
    h16x8 ap1 = *reinterpret_cast<const h16x8*>(pw + t16*72 + 32 + quad*8);
#pragma unroll
    for (int dc = 0; dc < 4; ++dc) {
      h16x8 bv0 = *reinterpret_cast<const h16x8*>(vt_sm + (dc*16 + t16)*64 + quad*8);
      h16x8 bv1 = *reinterpret_cast<const h16x8*>(vt_sm + (dc*16 + t16)*64 + 32 + quad*8);
      o_acc[dc] = mfma16(ap0, bv0, o_acc[dc]);
      o_acc[dc] = mfma16(ap1, bv1, o_acc[dc]);
    }
  }

  // partials (unnormalized) + (m,l)
  const size_t obase = ((size_t)jh*32 + bh) * 1024 * 64;
#pragma unroll
  for (int r = 0; r < 4; ++r) {
    int i = iw + quad*4 + r;
#pragma unroll
    for (int dc = 0; dc < 4; ++dc)
      o_part[obase + (size_t)i*64 + dc*16 + t16] = o_acc[dc][r];
    if (t16 == 0) {
      size_t mo = (((size_t)jh*32 + bh)*1024 + i)*2;
      ml_part[mo]     = m_run[r];
      ml_part[mo + 1] = l_run[r];
    }
  }
}

// ---------------- combine the 2 j-halves -> attn_h [(t*2+b)][E] h16 ----------------
__global__ __launch_bounds__(256) void combine_kernel(
    const float* __restrict__ o_part, const float* __restrict__ ml_part,
    h16* __restrict__ attn_h)
{
  int gid = blockIdx.x * 256 + threadIdx.x;   // 524288 total
  int row = gid >> 4;                          // (bh*1024 + i), 32768 rows
  int d4 = (gid & 15) * 4;
  float m1 = ml_part[row*2], l1 = ml_part[row*2 + 1];
  float m2 = ml_part[65536 + row*2], l2 = ml_part[65536 + row*2 + 1];
  float M = fmaxf(m1, m2);
  float e1 = __expf(m1 - M), e2 = __expf(m2 - M);
  float inv = 1.f / (e1*l1 + e2*l2);
  float4 O1 = *reinterpret_cast<const float4*>(o_part + (size_t)row*64 + d4);
  float4 O2 = *reinterpret_cast<const float4*>(o_part + 2097152 + (size_t)row*64 + d4);
  int bh = row >> 10, i = row & 1023, b = bh >> 4, h = bh & 15;
  h16x4 o = { (h16)((e1*O1.x + e2*O2.x) * inv), (h16)((e1*O1.y + e2*O2.y) * inv),
              (h16)((e1*O1.z + e2*O2.z) * inv), (h16)((e1*O1.w + e2*O2.w) * inv) };
  *reinterpret_cast<h16x4*>(attn_h + ((size_t)(i*2 + b))*1024 + h*64 + d4) = o;
}

extern "C" void kernel_launch(void* const* d_in, const int* in_sizes, int n_in,
                              void* d_out, int out_size, void* d_ws, size_t ws_size,
                              hipStream_t stream)
{
  const float* input  = (const float*)d_in[0];
  const float* pos    = (const float*)d_in[1];
  const float* fac    = (const float*)d_in[2];
  const float* w_in   = (const float*)d_in[3];
  const float* w_pos  = (const float*)d_in[4];
  const float* w_out  = (const float*)d_in[5];
  const float* bin_w  = (const float*)d_in[6];
  const float* bpos_w = (const float*)d_in[7];
  const float* bout_w = (const float*)d_in[8];
  const float* rw_w   = (const float*)d_in[9];
  const float* rr_w   = (const float*)d_in[10];
  float* out = (float*)d_out;
  (void)in_sizes; (void)n_in; (void)out_size; (void)ws_size;

  char* w = (char*)d_ws;
  auto take = [&](size_t bytes) { char* p = w; w += bytes; return p; };
  h16*   Win    = (h16*)take(3145728ull*2);
  h16*   Wpos   = (h16*)take(1048576ull*2);
  h16*   Wout   = (h16*)take(1048576ull*2);
  float* bin    = (float*)take(3072*4);
  float* bpos   = (float*)take(1024*4);
  float* bout   = (float*)take(1024*4);
  float* rw     = (float*)take(1024*4);
  float* rr     = (float*)take(1024*4);
  h16*   in_h   = (h16*)take(2097152ull*2);
  h16*   pos_h  = (h16*)take(4192256ull*2);   // OOB-read pad: buffers follow
  h16*   qrwb   = (h16*)take(2097152ull*2);
  h16*   qrrb   = (h16*)take(2097152ull*2);
  h16*   kb     = (h16*)take(2097152ull*2);
  h16*   vb     = (h16*)take(2097152ull*2);
  h16*   vbt    = (h16*)take(2097152ull*2);
  h16*   rb     = (h16*)take(4194304ull*2);
  float* o_part = (float*)take(4194304ull*4);
  float* ml     = (float*)take(131072ull*4);
  h16*   attn_h = (h16*)take(2097152ull*2);

  hypernet_kernel<<<20516, 256, 0, stream>>>(fac, w_in, w_pos, w_out, bin_w, bpos_w, bout_w,
                                             rw_w, rr_w, Win, Wpos, Wout, bin, bpos, bout,
                                             rw, rr, rb);
  cvt_f2h_kernel<<<2048, 256, 0, stream>>>(input, in_h, 524288);
  cvt_f2h_kernel<<<4094, 256, 0, stream>>>(pos, pos_h, 1048064);
  // qkv projection, fused split epilogue
  gemm_lds_kernel<0><<<dim3(24, 16), 256, 0, stream>>>(in_h, Win, bin, 2048, 3072, 1024,
                                                       nullptr, rw, rr, qrwb, qrrb, kb, vb);
  // r projection -> rb
  gemm_lds_kernel<1><<<dim3(8, 32), 256, 0, stream>>>(pos_h, Wpos, bpos, 4094, 1024, 1024,
                                                      nullptr, nullptr, nullptr, rb, nullptr, nullptr, nullptr);
  transpose_v_kernel<<<dim3(16, 32), 256, 0, stream>>>(vb, vbt);
  flash_kernel<<<dim3(16, 32, 2), 256, 0, stream>>>(qrwb, qrrb, kb, vbt, rb, o_part, ml);
  combine_kernel<<<2048, 256, 0, stream>>>(o_part, ml, attn_h);
  // out projection
  gemm_lds_kernel<2><<<dim3(8, 16), 256, 0, stream>>>(attn_h, Wout, bout, 2048, 1024, 1024,
                                                      out, nullptr, nullptr, nullptr, nullptr, nullptr, nullptr);
}

// Round 3
// 356.729 us; speedup vs baseline: 1.1041x; 1.0625x over previous
//
#include <hip/hip_runtime.h>

// MPRelativeSelfMultiheadAttn on gfx950.
// hypernet+casts (fused, BW-bound) -> fp16 MFMA GEMMs (global_load_lds with
// XOR-swizzled gather => conflict-free ds_read_b128) -> V transpose ->
// j-split(4) flash attention (rel_shift fused, online softmax) -> combine -> out GEMM.
// XOR swizzle: LDS(row, g) = global(row, g ^ (row&7)), granule = 16B.
// Fragment read granule = (kc*4+quad) ^ (t16&7): all 32 banks per 8-lane group.

typedef _Float16 h16;
typedef _Float16 h16x8 __attribute__((ext_vector_type(8)));
typedef _Float16 h16x4 __attribute__((ext_vector_type(4)));
typedef float f32x4 __attribute__((ext_vector_type(4)));

static __device__ __forceinline__ f32x4 mfma16(h16x8 a, h16x8 b, f32x4 c) {
  return __builtin_amdgcn_mfma_f32_16x16x32_f16(a, b, c, 0, 0, 0);
}
static __device__ __forceinline__ void gload16(const void* g, void* l) {
  __builtin_amdgcn_global_load_lds((const __attribute__((address_space(1))) void*)g,
                                   (__attribute__((address_space(3))) void*)l, 16, 0, 0);
}

// ---------------- hypernet + input casts (fused) ----------------
__global__ __launch_bounds__(256) void hypernet_kernel(
    const float* __restrict__ fac,
    const float* __restrict__ w_in, const float* __restrict__ w_pos,
    const float* __restrict__ w_out, const float* __restrict__ b_in_w,
    const float* __restrict__ b_pos_w, const float* __restrict__ b_out_w,
    const float* __restrict__ rw_w, const float* __restrict__ rr_w,
    h16* __restrict__ Win, h16* __restrict__ Wpos, h16* __restrict__ Wout,
    float* __restrict__ bin, float* __restrict__ bpos, float* __restrict__ bout,
    float* __restrict__ rw, float* __restrict__ rr, h16* __restrict__ rb,
    const float* __restrict__ input, h16* __restrict__ in_h,
    const float* __restrict__ pos, h16* __restrict__ pos_h)
{
  int idx = blockIdx.x * 256 + threadIdx.x;
  float f0=fac[0],f1=fac[1],f2=fac[2],f3=fac[3],f4=fac[4],f5=fac[5],f6=fac[6],f7=fac[7];
#define DOT8(p) ((p)[0]*f0+(p)[1]*f1+(p)[2]*f2+(p)[3]*f3+(p)[4]*f4+(p)[5]*f5+(p)[6]*f6+(p)[7]*f7)
  if (idx < 3145728) { const float* p = w_in  + (size_t)idx*8; Win[idx]  = (h16)DOT8(p); return; }
  idx -= 3145728;
  if (idx < 1048576) { const float* p = w_pos + (size_t)idx*8; Wpos[idx] = (h16)DOT8(p); return; }
  idx -= 1048576;
  if (idx < 1048576) { const float* p = w_out + (size_t)idx*8; Wout[idx] = (h16)DOT8(p); return; }
  idx -= 1048576;
  if (idx < 3072) { bin[idx]  = DOT8(b_in_w  + (size_t)idx*8); return; }
  idx -= 3072;
  if (idx < 1024) { bpos[idx] = DOT8(b_pos_w + (size_t)idx*8); return; }
  idx -= 1024;
  if (idx < 1024) { bout[idx] = DOT8(b_out_w + (size_t)idx*8); return; }
  idx -= 1024;
  if (idx < 1024) { rw[idx]   = DOT8(rw_w    + (size_t)idx*8); return; }
  idx -= 1024;
  if (idx < 1024) { rr[idx]   = DOT8(rr_w    + (size_t)idx*8); return; }
  idx -= 1024;
  if (idx < 2048) { rb[(((size_t)(idx >> 6)) << 17) + 2047*64 + (idx & 63)] = (h16)0.f; return; }
  idx -= 2048;
  if (idx < 524288) {
    float4 v = reinterpret_cast<const float4*>(input)[idx];
    h16x4 o = { (h16)v.x, (h16)v.y, (h16)v.z, (h16)v.w };
    reinterpret_cast<h16x4*>(in_h)[idx] = o;
    return;
  }
  idx -= 524288;
  if (idx < 1048064) {
    float4 v = reinterpret_cast<const float4*>(pos)[idx];
    h16x4 o = { (h16)v.x, (h16)v.y, (h16)v.z, (h16)v.w };
    reinterpret_cast<h16x4*>(pos_h)[idx] = o;
  }
#undef DOT8
}

// ---------------- GEMM C = A[MxK] * Bw[NxK]^T, swizzled global_load_lds ----------------
// MODE 0: qkv -> qrw,qrr,kb,vb per-head; MODE 1: r -> rb; MODE 2: fp32 C + bias
template <int MODE>
__global__ __launch_bounds__(256) void gemm_lds_kernel(
    const h16* __restrict__ A, const h16* __restrict__ Bw,
    const float* __restrict__ bias, int M, int N, int K,
    float* __restrict__ Cout,
    const float* __restrict__ rwv, const float* __restrict__ rrv,
    h16* __restrict__ o0, h16* __restrict__ o1,
    h16* __restrict__ o2, h16* __restrict__ o3)
{
  __shared__ __align__(16) h16 a_sm[128*64];
  __shared__ __align__(16) h16 b_sm[128*64];
  const int tid = threadIdx.x, lane = tid & 63, wave = tid >> 6;
  const int quad = lane >> 4, t16 = lane & 15;
  const int wm = wave >> 1, wn = wave & 1;
  const int m0 = blockIdx.y * 128, n0 = blockIdx.x * 128;
  const int lrow = lane >> 3, lgran = lane & 7;
  const int gsw = (lgran ^ lrow) * 8;          // swizzled source col offset (h16)
  const int xg0 = (quad ^ (t16 & 7)) * 8;      // fragment granule, kc=0
  const int xg1 = xg0 ^ 32;                    // kc=1

  f32x4 acc[4][4];
#pragma unroll
  for (int i = 0; i < 4; ++i)
#pragma unroll
    for (int j = 0; j < 4; ++j) acc[i][j] = (f32x4){0.f,0.f,0.f,0.f};

  for (int k0 = 0; k0 < K; k0 += 64) {
    __syncthreads();
#pragma unroll
    for (int s = 0; s < 4; ++s) {
      int rbase = wave*32 + s*8;
      gload16(A  + (size_t)(m0 + rbase + lrow)*K + k0 + gsw, a_sm + rbase*64);
      gload16(Bw + (size_t)(n0 + rbase + lrow)*K + k0 + gsw, b_sm + rbase*64);
    }
    __syncthreads();
#pragma unroll
    for (int kc = 0; kc < 2; ++kc) {
      const int xg = kc ? xg1 : xg0;
      h16x8 af[4], bfr[4];
#pragma unroll
      for (int i = 0; i < 4; ++i) {
        af[i]  = *reinterpret_cast<const h16x8*>(a_sm + (wm*64 + i*16 + t16)*64 + xg);
        bfr[i] = *reinterpret_cast<const h16x8*>(b_sm + (wn*64 + i*16 + t16)*64 + xg);
      }
#pragma unroll
      for (int i = 0; i < 4; ++i)
#pragma unroll
        for (int j = 0; j < 4; ++j)
          acc[i][j] = mfma16(af[i], bfr[j], acc[i][j]);
    }
  }

  // epilogue: C/D layout row=(lane>>4)*4+reg, col=lane&15
#pragma unroll
  for (int i = 0; i < 4; ++i) {
    int mb = m0 + wm*64 + i*16 + quad*4;
#pragma unroll
    for (int j = 0; j < 4; ++j) {
      int n = n0 + wn*64 + j*16 + t16;
      float bv = bias[n];
      if (MODE == 2) {
#pragma unroll
        for (int r = 0; r < 4; ++r)
          Cout[(size_t)(mb + r)*N + n] = acc[i][j][r] + bv;
      } else if (MODE == 0) {
        int nn = n & 1023, sec = n >> 10, hh = nn >> 6, d = nn & 63;
        float rwb = rwv[nn], rrb = rrv[nn];
#pragma unroll
        for (int r = 0; r < 4; ++r) {
          int m = mb + r, t = m >> 1, b = m & 1;
          size_t off = ((size_t)((b << 4) + hh) << 16) + (t << 6) + d;
          float v = acc[i][j][r] + bv;
          if (sec == 0)      { o0[off] = (h16)(v + rwb); o1[off] = (h16)(v + rrb); }
          else if (sec == 1) { o2[off] = (h16)v; }
          else               { o3[off] = (h16)v; }
        }
      } else { // MODE 1
        int hh = n >> 6, d = n & 63;
#pragma unroll
        for (int r = 0; r < 4; ++r) {
          int m = mb + r;
          if (m < M) {
            int rel = m >> 1, b = m & 1;
            o0[(((size_t)((b << 4) + hh)) << 17) + (rel << 6) + d] = (h16)(acc[i][j][r] + bv);
          }
        }
      }
    }
  }
}

// ---------------- V transpose: vb [BH][T][64] -> vbt [BH][64][T] ----------------
__global__ __launch_bounds__(256) void transpose_v_kernel(
    const h16* __restrict__ vb, h16* __restrict__ vbt)
{
  __shared__ h16 tile[64*72];
  const int bh = blockIdx.y, t0 = blockIdx.x * 64;
  const int r = threadIdx.x >> 3, c = (threadIdx.x & 7) * 8;
  const h16* src = vb + ((size_t)bh << 16) + (size_t)(t0 + r)*64 + c;
  *reinterpret_cast<h16x8*>(tile + r*72 + c)        = *reinterpret_cast<const h16x8*>(src);
  *reinterpret_cast<h16x8*>(tile + (r + 32)*72 + c) = *reinterpret_cast<const h16x8*>(src + 32*64);
  __syncthreads();
  h16x8 o0, o1;
#pragma unroll
  for (int e = 0; e < 8; ++e) {
    o0[e] = tile[(c + e)*72 + r];
    o1[e] = tile[(c + e)*72 + r + 32];
  }
  h16* dst = vbt + ((size_t)bh << 16) + (size_t)r*1024 + t0 + c;
  *reinterpret_cast<h16x8*>(dst)            = o0;
  *reinterpret_cast<h16x8*>(dst + 32*1024)  = o1;
}

// ---------------- flash attention, j-split(4), swizzled staging ----------------
__global__ __launch_bounds__(256) void flash_kernel(
    const h16* __restrict__ qrw, const h16* __restrict__ qrr,
    const h16* __restrict__ kb, const h16* __restrict__ vbt,
    const h16* __restrict__ rb,
    float* __restrict__ o_part, float* __restrict__ ml_part)
{
  __shared__ __align__(16) h16 k_sm[64*64];
  __shared__ __align__(16) h16 vt_sm[64*64];
  __shared__ __align__(16) h16 r_sm[128*64];   // reused as BD/P spill after barrier

  const int tid = threadIdx.x, lane = tid & 63, wave = tid >> 6;
  const int quad = lane >> 4, t16 = lane & 15;
  const int bh = blockIdx.y, i0 = blockIdx.x * 64, jh = blockIdx.z;
  const size_t base  = (size_t)bh << 16;
  const size_t rbase = (size_t)bh << 17;
  const int iw = i0 + wave * 16;
  const int lrow = lane >> 3, lgran = lane & 7;
  const int gsw = (lgran ^ lrow) * 8;
  const int xg0 = (quad ^ (t16 & 7)) * 8;
  const int xg1 = xg0 ^ 32;

  h16x8 a_rw[2], a_rr[2];
  {
    const h16* p = qrw + base + (size_t)(iw + t16)*64 + quad*8;
    a_rw[0] = *reinterpret_cast<const h16x8*>(p);
    a_rw[1] = *reinterpret_cast<const h16x8*>(p + 32);
    const h16* p2 = qrr + base + (size_t)(iw + t16)*64 + quad*8;
    a_rr[0] = *reinterpret_cast<const h16x8*>(p2);
    a_rr[1] = *reinterpret_cast<const h16x8*>(p2 + 32);
  }

  f32x4 o_acc[4];
#pragma unroll
  for (int dc = 0; dc < 4; ++dc) o_acc[dc] = (f32x4){0.f,0.f,0.f,0.f};
  float m_run[4] = {-1e30f,-1e30f,-1e30f,-1e30f};
  float l_run[4] = {0.f,0.f,0.f,0.f};   // per-lane partial; reduced at end

  h16* bdw = r_sm + wave * (16*84);
  const int cb0 = 3 - wave;

  for (int j0 = jh*256; j0 < jh*256 + 256; j0 += 64) {
    __syncthreads();
    { // swizzled staging
#pragma unroll
      for (int s = 0; s < 2; ++s) {
        int row = wave*16 + s*8;
        gload16(kb  + base + (size_t)(j0 + row + lrow)*64 + gsw, k_sm  + row*64);
        gload16(vbt + base + (size_t)(row + lrow)*1024 + j0 + gsw, vt_sm + row*64);
      }
      const int rel0 = j0 - i0 + 960;
#pragma unroll
      for (int s = 0; s < 4; ++s) {
        int row = wave*32 + s*8;
        gload16(rb + rbase + (size_t)(rel0 + row + lrow)*64 + gsw, r_sm + row*64);
      }
    }
    __syncthreads();

    f32x4 s_ac[4];
#pragma unroll
    for (int c = 0; c < 4; ++c) {
      s_ac[c] = (f32x4){0.f,0.f,0.f,0.f};
      s_ac[c] = mfma16(a_rw[0], *reinterpret_cast<const h16x8*>(k_sm + (c*16 + t16)*64 + xg0), s_ac[c]);
      s_ac[c] = mfma16(a_rw[1], *reinterpret_cast<const h16x8*>(k_sm + (c*16 + t16)*64 + xg1), s_ac[c]);
    }
    f32x4 s_bd[5];
#pragma unroll
    for (int u = 0; u < 5; ++u) {
      s_bd[u] = (f32x4){0.f,0.f,0.f,0.f};
      s_bd[u] = mfma16(a_rr[0], *reinterpret_cast<const h16x8*>(r_sm + ((cb0+u)*16 + t16)*64 + xg0), s_bd[u]);
      s_bd[u] = mfma16(a_rr[1], *reinterpret_cast<const h16x8*>(r_sm + ((cb0+u)*16 + t16)*64 + xg1), s_bd[u]);
    }
    __syncthreads();  // r_sm reads done before spilling into it

    // BD spill (C-layout), stride 84
#pragma unroll
    for (int u = 0; u < 5; ++u)
#pragma unroll
      for (int r = 0; r < 4; ++r)
        bdw[(quad*4 + r)*84 + u*16 + t16] = (h16)s_bd[u][r];

    // combine with relative shift
    float sv[4][4];
#pragma unroll
    for (int c = 0; c < 4; ++c)
#pragma unroll
      for (int r = 0; r < 4; ++r) {
        int il = quad*4 + r;
        float bdv = (float)bdw[il*84 + c*16 + t16 + 15 - il];
        sv[c][r] = (s_ac[c][r] + bdv) * 0.125f;
      }

    // online softmax: shared row max (shfl), per-lane l partial
    float alpha[4];
#pragma unroll
    for (int r = 0; r < 4; ++r) {
      float v = fmaxf(fmaxf(sv[0][r], sv[1][r]), fmaxf(sv[2][r], sv[3][r]));
#pragma unroll
      for (int off = 1; off < 16; off <<= 1) v = fmaxf(v, __shfl_xor(v, off, 64));
      float mn = fmaxf(m_run[r], v);
      alpha[r] = __expf(m_run[r] - mn);
      m_run[r] = mn;
    }
#pragma unroll
    for (int r = 0; r < 4; ++r) {
      float s0 = 0.f;
#pragma unroll
      for (int c = 0; c < 4; ++c) {
        float p = __expf(sv[c][r] - m_run[r]);
        sv[c][r] = p; s0 += p;
      }
      l_run[r] = l_run[r]*alpha[r] + s0;   // per-lane; reduce at end
    }
#pragma unroll
    for (int dc = 0; dc < 4; ++dc) {
      f32x4 t = o_acc[dc];
#pragma unroll
      for (int r = 0; r < 4; ++r) t[r] *= alpha[r];
      o_acc[dc] = t;
    }
    // P round-trip (stride 72, 2-way free)
    h16* pw = bdw;
#pragma unroll
    for (int c = 0; c < 4; ++c)
#pragma unroll
      for (int r = 0; r < 4; ++r)
        pw[(quad*4 + r)*72 + c*16 + t16] = (h16)sv[c][r];

    h16x8 ap0 = *reinterpret_cast<const h16x8*>(pw + t16*72 + quad*8);
    h16x8 ap1 = *reinterpret_cast<const h16x8*>(pw + t16*72 + 32 + quad*8);
#pragma unroll
    for (int dc = 0; dc < 4; ++dc) {
      h16x8 bv0 = *reinterpret_cast<const h16x8*>(vt_sm + (dc*16 + t16)*64 + xg0);
      h16x8 bv1 = *reinterpret_cast<const h16x8*>(vt_sm + (dc*16 + t16)*64 + xg1);
      o_acc[dc] = mfma16(ap0, bv0, o_acc[dc]);
      o_acc[dc] = mfma16(ap1, bv1, o_acc[dc]);
    }
  }

  // reduce l across the quad's 16 lanes, then write partials
#pragma unroll
  for (int r = 0; r < 4; ++r) {
    float l = l_run[r];
#pragma unroll
    for (int off = 1; off < 16; off <<= 1) l += __shfl_xor(l, off, 64);
    l_run[r] = l;
  }
  const size_t obase = ((size_t)jh*32 + bh) * 1024 * 64;
#pragma unroll
  for (int r = 0; r < 4; ++r) {
    int i = iw + quad*4 + r;
#pragma unroll
    for (int dc = 0; dc < 4; ++dc)
      o_part[obase + (size_t)i*64 + dc*16 + t16] = o_acc[dc][r];
    if (t16 == 0) {
      size_t mo = (((size_t)jh*32 + bh)*1024 + i)*2;
      ml_part[mo]     = m_run[r];
      ml_part[mo + 1] = l_run[r];
    }
  }
}

// ---------------- combine 4 j-parts -> attn_h [(t*2+b)][E] h16 ----------------
__global__ __launch_bounds__(256) void combine_kernel(
    const float* __restrict__ o_part, const float* __restrict__ ml_part,
    h16* __restrict__ attn_h)
{
  int gid = blockIdx.x * 256 + threadIdx.x;   // 524288
  int row = gid >> 4;                          // bh*1024 + i
  int d4 = (gid & 15) * 4;
  float m[4], l[4];
#pragma unroll
  for (int p = 0; p < 4; ++p) {
    m[p] = ml_part[p*65536 + row*2];
    l[p] = ml_part[p*65536 + row*2 + 1];
  }
  float M = fmaxf(fmaxf(m[0], m[1]), fmaxf(m[2], m[3]));
  float e[4], den = 0.f;
#pragma unroll
  for (int p = 0; p < 4; ++p) { e[p] = __expf(m[p] - M); den += e[p]*l[p]; }
  float inv = 1.f / den;
  float4 acc = {0.f,0.f,0.f,0.f};
#pragma unroll
  for (int p = 0; p < 4; ++p) {
    float4 O = *reinterpret_cast<const float4*>(o_part + (size_t)p*2097152 + (size_t)row*64 + d4);
    acc.x += e[p]*O.x; acc.y += e[p]*O.y; acc.z += e[p]*O.z; acc.w += e[p]*O.w;
  }
  int bh = row >> 10, i = row & 1023, b = bh >> 4, h = bh & 15;
  h16x4 o = { (h16)(acc.x*inv), (h16)(acc.y*inv), (h16)(acc.z*inv), (h16)(acc.w*inv) };
  *reinterpret_cast<h16x4*>(attn_h + ((size_t)(i*2 + b))*1024 + h*64 + d4) = o;
}

extern "C" void kernel_launch(void* const* d_in, const int* in_sizes, int n_in,
                              void* d_out, int out_size, void* d_ws, size_t ws_size,
                              hipStream_t stream)
{
  const float* input  = (const float*)d_in[0];
  const float* pos    = (const float*)d_in[1];
  const float* fac    = (const float*)d_in[2];
  const float* w_in   = (const float*)d_in[3];
  const float* w_pos  = (const float*)d_in[4];
  const float* w_out  = (const float*)d_in[5];
  const float* bin_w  = (const float*)d_in[6];
  const float* bpos_w = (const float*)d_in[7];
  const float* bout_w = (const float*)d_in[8];
  const float* rw_w   = (const float*)d_in[9];
  const float* rr_w   = (const float*)d_in[10];
  float* out = (float*)d_out;
  (void)in_sizes; (void)n_in; (void)out_size; (void)ws_size;

  char* w = (char*)d_ws;
  auto take = [&](size_t bytes) { char* p = w; w += bytes; return p; };
  h16*   Win    = (h16*)take(3145728ull*2);
  h16*   Wpos   = (h16*)take(1048576ull*2);
  h16*   Wout   = (h16*)take(1048576ull*2);
  float* bin    = (float*)take(3072*4);
  float* bpos   = (float*)take(1024*4);
  float* bout   = (float*)take(1024*4);
  float* rw     = (float*)take(1024*4);
  float* rr     = (float*)take(1024*4);
  h16*   in_h   = (h16*)take(2097152ull*2);
  h16*   pos_h  = (h16*)take(4192256ull*2);   // OOB-read pad: buffers follow
  h16*   qrwb   = (h16*)take(2097152ull*2);
  h16*   qrrb   = (h16*)take(2097152ull*2);
  h16*   kb     = (h16*)take(2097152ull*2);
  h16*   vb     = (h16*)take(2097152ull*2);
  h16*   vbt    = (h16*)take(2097152ull*2);
  h16*   rb     = (h16*)take(4194304ull*2);
  float* o_part = (float*)take(4ull*2097152ull*4);
  float* ml     = (float*)take(4ull*65536ull*4);
  h16*   attn_h = (h16*)take(2097152ull*2);

  hypernet_kernel<<<26658, 256, 0, stream>>>(fac, w_in, w_pos, w_out, bin_w, bpos_w, bout_w,
                                             rw_w, rr_w, Win, Wpos, Wout, bin, bpos, bout,
                                             rw, rr, rb, input, in_h, pos, pos_h);
  gemm_lds_kernel<0><<<dim3(24, 16), 256, 0, stream>>>(in_h, Win, bin, 2048, 3072, 1024,
                                                       nullptr, rw, rr, qrwb, qrrb, kb, vb);
  gemm_lds_kernel<1><<<dim3(8, 32), 256, 0, stream>>>(pos_h, Wpos, bpos, 4094, 1024, 1024,
                                                      nullptr, nullptr, nullptr, rb, nullptr, nullptr, nullptr);
  transpose_v_kernel<<<dim3(16, 32), 256, 0, stream>>>(vb, vbt);
  flash_kernel<<<dim3(16, 32, 4), 256, 0, stream>>>(qrwb, qrrb, kb, vbt, rb, o_part, ml);
  combine_kernel<<<2048, 256, 0, stream>>>(o_part, ml, attn_h);
  gemm_lds_kernel<2><<<dim3(8, 16), 256, 0, stream>>>(attn_h, Wout, bout, 2048, 1024, 1024,
                                                      out, nullptr, nullptr, nullptr, nullptr, nullptr, nullptr);
}